// Round 1
// baseline (297.973 us; speedup 1.0000x reference)
//
#include <hip/hip_runtime.h>
#include <hip/hip_bf16.h>

#define T 128
#define CIN 128
#define C 256
#define NBE 1024  // B*E = 4*256

typedef short bf8_t __attribute__((ext_vector_type(8)));
typedef float f4_t __attribute__((ext_vector_type(4)));

__device__ inline short f2bf(float f) {
  union { float f; unsigned u; } v; v.f = f;
  unsigned r = v.u + 0x7FFFu + ((v.u >> 16) & 1u);
  return (short)(r >> 16);
}
__device__ inline float bf2f(short s) {
  union { unsigned u; float f; } v; v.u = ((unsigned)(unsigned short)s) << 16;
  return v.f;
}
__device__ inline f4_t mfma16(bf8_t a, bf8_t b, f4_t c) {
  return __builtin_amdgcn_mfma_f32_16x16x32_bf16(a, b, c, 0, 0, 0);
}
// LDS bf16 tile frag load, XOR-swizzled rows: short index col ^ ((row&7)<<3).
// kcol is a multiple of 8 so the 16B read stays aligned and the XOR (bits 3-5)
// is constant across the 8 consecutive shorts.
__device__ inline bf8_t lds_frag(const short* base, int row, int kcol, int rowc) {
  return *reinterpret_cast<const bf8_t*>(base + row * rowc + (kcol ^ ((row & 7) << 3)));
}

__global__ void prep_weights(const float* __restrict__ Wp, const float* __restrict__ Wb,
                             const float* __restrict__ Wg, const float* __restrict__ Wd,
                             short* __restrict__ ws) {
  int i = blockIdx.x * 256 + threadIdx.x;  // grid 256*256 = 65536
  if (i < 32768) ws[i] = f2bf(Wp[i]);      // Wp [256][128]
  ws[32768 + i]  = f2bf(Wb[i]);            // Wb [256][256]
  ws[98304 + i]  = f2bf(Wg[i]);
  ws[163840 + i] = f2bf(Wd[i]);
}

__global__ __launch_bounds__(512, 1) void fused_ssm(
    const float* __restrict__ xe, const short* __restrict__ wgt,
    const float* __restrict__ bp, const float* __restrict__ a_param,
    const float* __restrict__ bb, const float* __restrict__ bg,
    const float* __restrict__ bd, const float* __restrict__ gamma,
    const float* __restrict__ beta, const float* __restrict__ rmean,
    const float* __restrict__ rvar, float* __restrict__ out) {
  __shared__ __align__(16) short lds_x[T * C];  // 64 KiB: x (bf16, swizzled)
  __shared__ __align__(16) short lds_u[T * C];  // 64 KiB: xe then u/S
  short* lds_xe = lds_u;                        // xe aliases u (dead after GEMM1)

  const int tid = threadIdx.x;
  const int lane = tid & 63;
  const int w = tid >> 6;   // 0..7
  const int wr = w >> 1;    // 0..3: rows [wr*32, wr*32+32)
  const int wc = w & 1;     // 0..1: cols [wc*128, wc*128+128)
  const int l15 = lane & 15;
  const int l4 = lane >> 4; // 0..3
  const int be = blockIdx.x;

  const float* xe_blk = xe + (size_t)be * T * CIN;
  float* out_blk = out + (size_t)be * T * C;

  const short* Wpb = wgt;           // [256][128]  (N-major, K-contig == B^T)
  const short* Wbb = wgt + 32768;   // [256][256]
  const short* Wgb = wgt + 98304;   // [256][256]
  const short* Wdb = wgt + 163840;  // [256][256]

  // ---- stage x_e -> LDS bf16 (swizzled) ----
#pragma unroll
  for (int j = 0; j < 32; ++j) {
    int idx = j * 512 + tid;
    int r = idx >> 7, c = idx & 127;
    lds_xe[r * 128 + (c ^ ((r & 7) << 3))] = f2bf(xe_blk[idx]);
  }
  __syncthreads();

  const int row_a0 = wr * 32 + l15;  // A-frag row (mi=0)
  const int col0 = wc * 128 + l15;   // D/B col base (add ni*16)

  f4_t acc[2][8];

  // ================= GEMM1: x = xe @ Wp^T + bp  (K=128) =================
#pragma unroll
  for (int mi = 0; mi < 2; ++mi)
#pragma unroll
    for (int ni = 0; ni < 8; ++ni) acc[mi][ni] = (f4_t)(0.f);

#pragma unroll
  for (int kk = 0; kk < 4; ++kk) {
    int kcol = kk * 32 + l4 * 8;
    bf8_t a0 = lds_frag(lds_xe, row_a0, kcol, 128);
    bf8_t a1 = lds_frag(lds_xe, row_a0 + 16, kcol, 128);
#pragma unroll
    for (int ni = 0; ni < 8; ++ni) {
      bf8_t b = *reinterpret_cast<const bf8_t*>(Wpb + (col0 + ni * 16) * 128 + kcol);
      acc[0][ni] = mfma16(a0, b, acc[0][ni]);
      acc[1][ni] = mfma16(a1, b, acc[1][ni]);
    }
  }
  // store x (+bp) to lds_x (bf16, swizzled)
#pragma unroll
  for (int ni = 0; ni < 8; ++ni) {
    int col = col0 + ni * 16;
    float bias = bp[col];
#pragma unroll
    for (int mi = 0; mi < 2; ++mi)
#pragma unroll
      for (int r = 0; r < 4; ++r) {
        int row = wr * 32 + mi * 16 + l4 * 4 + r;
        lds_x[row * 256 + (col ^ ((row & 7) << 3))] = f2bf(acc[mi][ni][r] + bias);
      }
  }
  __syncthreads();

  // ================= GEMM2: u = x @ Wb^T + bb  (K=256) =================
#pragma unroll
  for (int mi = 0; mi < 2; ++mi)
#pragma unroll
    for (int ni = 0; ni < 8; ++ni) acc[mi][ni] = (f4_t)(0.f);

#pragma unroll
  for (int kk = 0; kk < 8; ++kk) {
    int kcol = kk * 32 + l4 * 8;
    bf8_t a0 = lds_frag(lds_x, row_a0, kcol, 256);
    bf8_t a1 = lds_frag(lds_x, row_a0 + 16, kcol, 256);
#pragma unroll
    for (int ni = 0; ni < 8; ++ni) {
      bf8_t b = *reinterpret_cast<const bf8_t*>(Wbb + (col0 + ni * 16) * 256 + kcol);
      acc[0][ni] = mfma16(a0, b, acc[0][ni]);
      acc[1][ni] = mfma16(a1, b, acc[1][ni]);
    }
  }
  // store u (+bb) to lds_u (overwrites dead xe region)
#pragma unroll
  for (int ni = 0; ni < 8; ++ni) {
    int col = col0 + ni * 16;
    float bias = bb[col];
#pragma unroll
    for (int mi = 0; mi < 2; ++mi)
#pragma unroll
      for (int r = 0; r < 4; ++r) {
        int row = wr * 32 + mi * 16 + l4 * 4 + r;
        lds_u[row * 256 + (col ^ ((row & 7) << 3))] = f2bf(acc[mi][ni][r] + bias);
      }
  }
  __syncthreads();

  // ================= recurrence: s_t = a*s_{t-1} + u_t (in-place u->S) ====
  if (tid < 256) {
    float a = tanhf(a_param[tid]);
    float s = 0.f;
    for (int t = 0; t < T; ++t) {
      int idx = t * 256 + (tid ^ ((t & 7) << 3));
      s = a * s + bf2f(lds_u[idx]);
      lds_u[idx] = f2bf(s);  // state stays fp32 in reg; only storage is bf16
    }
  }
  __syncthreads();

  // ========== GEMM3+4: y = S @ Wg^T + x @ Wd^T  (K=256, shared acc) ======
#pragma unroll
  for (int mi = 0; mi < 2; ++mi)
#pragma unroll
    for (int ni = 0; ni < 8; ++ni) acc[mi][ni] = (f4_t)(0.f);

#pragma unroll
  for (int kk = 0; kk < 8; ++kk) {
    int kcol = kk * 32 + l4 * 8;
    bf8_t s0 = lds_frag(lds_u, row_a0, kcol, 256);
    bf8_t s1 = lds_frag(lds_u, row_a0 + 16, kcol, 256);
    bf8_t x0 = lds_frag(lds_x, row_a0, kcol, 256);
    bf8_t x1 = lds_frag(lds_x, row_a0 + 16, kcol, 256);
#pragma unroll
    for (int ni = 0; ni < 8; ++ni) {
      bf8_t bgf = *reinterpret_cast<const bf8_t*>(Wgb + (col0 + ni * 16) * 256 + kcol);
      acc[0][ni] = mfma16(s0, bgf, acc[0][ni]);
      acc[1][ni] = mfma16(s1, bgf, acc[1][ni]);
      bf8_t bdf = *reinterpret_cast<const bf8_t*>(Wdb + (col0 + ni * 16) * 256 + kcol);
      acc[0][ni] = mfma16(x0, bdf, acc[0][ni]);
      acc[1][ni] = mfma16(x1, bdf, acc[1][ni]);
    }
  }

  // ================= epilogue: +bg+bd, BN(eval), exact GELU, +x ==========
#pragma unroll
  for (int ni = 0; ni < 8; ++ni) {
    int col = col0 + ni * 16;
    float bsum = bg[col] + bd[col];
    float mu = rmean[col];
    float rstd = rsqrtf(rvar[col] + 1e-5f);
    float ga = gamma[col], bt = beta[col];
#pragma unroll
    for (int mi = 0; mi < 2; ++mi)
#pragma unroll
      for (int r = 0; r < 4; ++r) {
        int row = wr * 32 + mi * 16 + l4 * 4 + r;
        float y = acc[mi][ni][r] + bsum;
        y = (y - mu) * rstd * ga + bt;
        float g = 0.5f * y * (1.f + erff(y * 0.70710678118654752f));
        float xv = bf2f(lds_x[row * 256 + (col ^ ((row & 7) << 3))]);
        out_blk[row * 256 + col] = g + xv;
      }
  }
}

extern "C" void kernel_launch(void* const* d_in, const int* in_sizes, int n_in,
                              void* d_out, int out_size, void* d_ws, size_t ws_size,
                              hipStream_t stream) {
  const float* xe    = (const float*)d_in[0];
  const float* Wp    = (const float*)d_in[1];
  const float* bp    = (const float*)d_in[2];
  const float* ap    = (const float*)d_in[3];
  const float* Wb    = (const float*)d_in[4];
  const float* bb    = (const float*)d_in[5];
  const float* Wg    = (const float*)d_in[6];
  const float* bg    = (const float*)d_in[7];
  const float* Wd    = (const float*)d_in[8];
  const float* bd    = (const float*)d_in[9];
  const float* gamma = (const float*)d_in[10];
  const float* beta  = (const float*)d_in[11];
  const float* rmean = (const float*)d_in[12];
  const float* rvar  = (const float*)d_in[13];
  float* out = (float*)d_out;
  short* wgt = (short*)d_ws;  // 229376 shorts = 448 KiB of bf16 weights

  prep_weights<<<256, 256, 0, stream>>>(Wp, Wb, Wg, Wd, wgt);
  fused_ssm<<<NBE, 512, 0, stream>>>(xe, wgt, bp, ap, bb, bg, bd, gamma, beta,
                                     rmean, rvar, out);
}